// Round 10
// baseline (108.528 us; speedup 1.0000x reference)
//
#include <hip/hip_runtime.h>
#include <hip/hip_bf16.h>

// Problem constants: B=8, NUM=4 -> BB=32 batches; LQ=128, LP=512, H=512.
#define BBATCH 32
#define LQ 128
#define LP 512
#define HDIM 512
#define GDIM 2560   // 5*H concat width
#define NEG_MAX (-3.402823466e38f)

typedef __attribute__((ext_vector_type(8))) short short8;
typedef __attribute__((ext_vector_type(4))) float f32x4;
typedef __attribute__((ext_vector_type(4))) unsigned short ushort4v;

__device__ inline unsigned short f2bf(float f) {
  union { float f; unsigned int u; } v; v.f = f;
  unsigned int r = v.u + 0x7FFFu + ((v.u >> 16) & 1u);  // RNE
  return (unsigned short)(r >> 16);
}

// ---- staging / fragment helpers (rows x 64 k bf16 tiles, XOR-swizzled, 128B rows) ----
__device__ inline void stage128x64(const unsigned short* __restrict__ src, int ld,
                                   int row0, int k0, unsigned short* lds, int t) {
#pragma unroll
  for (int i = 0; i < 4; i++) {
    int o = (t + i * 256) * 16;
    int row = o >> 7, col = (o & 127) >> 1;
    int swz = o ^ ((row & 7) << 4);
    *(short8*)((char*)lds + swz) = *(const short8*)(src + (long)(row0 + row) * ld + k0 + col);
  }
}
// f32 source -> bf16 LDS (convert in-register)
__device__ inline void stage64x64_f32(const float* __restrict__ src, int ld,
                                      int row0, int k0, unsigned short* lds, int t) {
#pragma unroll
  for (int i = 0; i < 2; i++) {
    int o = (t + i * 256) * 16;
    int row = o >> 7, col = (o & 127) >> 1;
    int swz = o ^ ((row & 7) << 4);
    const float* p = src + (long)(row0 + row) * ld + k0 + col;
    float4 a = *(const float4*)p;
    float4 b2 = *(const float4*)(p + 4);
    short8 v = {(short)f2bf(a.x), (short)f2bf(a.y), (short)f2bf(a.z), (short)f2bf(a.w),
                (short)f2bf(b2.x), (short)f2bf(b2.y), (short)f2bf(b2.z), (short)f2bf(b2.w)};
    *(short8*)((char*)lds + swz) = v;
  }
}
__device__ inline short8 fragld(const unsigned short* lds, int row, int ks, int fq) {
  return *(const short8*)((const char*)lds + (((row << 7) + ks * 64 + fq * 16) ^ ((row & 7) << 4)));
}

// ---------------- prep: Ep & Eq f32 -> bf16 transposed (+ Eqw) + exact f32 bias dots ----------------
__global__ __launch_bounds__(256) void prep_kernel(
    const float* __restrict__ Ep, const float* __restrict__ Eq,
    const float* __restrict__ w,
    unsigned short* __restrict__ EpT, unsigned short* __restrict__ EqT,
    unsigned short* __restrict__ Eqw,
    float* __restrict__ epv, float* __restrict__ eqv) {
  const int b = blockIdx.y;
  const int bx = blockIdx.x;
  const bool isP = bx < 8;
  const int R = isP ? LP : LQ;
  const int p0 = (isP ? bx : bx - 8) * 64;
  const float* src = isP ? Ep + (long)b * LP * HDIM : Eq + (long)b * LQ * HDIM;
  const float* wb_base = isP ? w + HDIM : w;
  unsigned short* dT = isP ? EpT + (long)b * HDIM * LP : EqT + (long)b * HDIM * LQ;
  unsigned short* dW = isP ? nullptr : Eqw + (long)b * LQ * HDIM;
  float* bias = (isP ? epv + b * LP : eqv + b * LQ) + p0;
  __shared__ float T[64][65];
  const int t = threadIdx.x, c4 = (t & 15) * 4, r = t >> 4;
  float dot[4] = {0.f, 0.f, 0.f, 0.f};
  for (int h0 = 0; h0 < HDIM; h0 += 64) {
    float4 wb = *(const float4*)(wb_base + h0 + c4);
    float4 wm4 = {0, 0, 0, 0};
    if (!isP) wm4 = *(const float4*)(w + 2 * HDIM + h0 + c4);
    __syncthreads();
#pragma unroll
    for (int i = 0; i < 4; i++) {
      int row = r + 16 * i;
      float4 v = *(const float4*)(src + (long)(p0 + row) * HDIM + h0 + c4);
      T[row][c4] = v.x; T[row][c4 + 1] = v.y; T[row][c4 + 2] = v.z; T[row][c4 + 3] = v.w;
      if (!isP) {
        ushort4v ow = {f2bf(v.x * wm4.x), f2bf(v.y * wm4.y), f2bf(v.z * wm4.z), f2bf(v.w * wm4.w)};
        *(ushort4v*)(dW + (long)(p0 + row) * HDIM + h0 + c4) = ow;
      }
      dot[i] += v.x * wb.x + v.y * wb.y + v.z * wb.z + v.w * wb.w;
    }
    __syncthreads();
#pragma unroll
    for (int i = 0; i < 4; i++) {
      int hh = r + 16 * i;
      ushort4v o = {f2bf(T[c4][hh]), f2bf(T[c4 + 1][hh]), f2bf(T[c4 + 2][hh]), f2bf(T[c4 + 3][hh])};
      *(ushort4v*)(dT + (long)(h0 + hh) * R + p0 + c4) = o;
    }
  }
#pragma unroll
  for (int i = 0; i < 4; i++) {
#pragma unroll
    for (int s = 1; s < 16; s <<= 1) dot[i] += __shfl_xor(dot[i], s);
  }
  if ((t & 15) == 0) {
#pragma unroll
    for (int i = 0; i < 4; i++) bias[r + 16 * i] = dot[i];
  }
}

// ---------------- U GEMM (64-row M-tile) + fused row-softmax ----------------
// Outputs: Apb [p][q], ApT [q][p] bf16; UmT [q][p] f32.
__global__ __launch_bounds__(256) void u_gemm(
    const float* __restrict__ EpF, const unsigned short* __restrict__ Bb,
    const float* __restrict__ epv, const float* __restrict__ eqv,
    const int* __restrict__ maskM, const int* __restrict__ maskN,
    float* __restrict__ UmT, unsigned short* __restrict__ Apb,
    unsigned short* __restrict__ ApT) {
  const int hw = blockIdx.x;
  const int xcd = hw & 7, s_ = hw >> 3;
  const int b = xcd * 4 + (s_ >> 3);
  const int m0 = (s_ & 7) * 64;
  const float* A = EpF + (long)b * LP * HDIM;
  const unsigned short* B = Bb + (long)b * LQ * HDIM;
  __shared__ unsigned short As[4096];  // 64 x 64
  __shared__ unsigned short Bs[8192];  // 128 x 64
  __shared__ float smax[2][64], ssum[2][64];
  const int t = threadIdx.x, lane = t & 63, wid = t >> 6;
  const int wm = wid >> 1, wn = wid & 1;
  const int wr = wm * 32, wc = wn * 64;
  const int fr = lane & 15, fq = lane >> 4;
  f32x4 acc[2][4] = {};
  for (int k0 = 0; k0 < HDIM; k0 += 64) {
    stage64x64_f32(A, HDIM, m0, k0, As, t);
    stage128x64(B, HDIM, 0, k0, Bs, t);
    __syncthreads();
#pragma unroll
    for (int ks = 0; ks < 2; ks++) {
      short8 af[2], bfv[4];
#pragma unroll
      for (int i = 0; i < 2; i++) af[i] = fragld(As, wr + i * 16 + fr, ks, fq);
#pragma unroll
      for (int j = 0; j < 4; j++) bfv[j] = fragld(Bs, wc + j * 16 + fr, ks, fq);
#pragma unroll
      for (int i = 0; i < 2; i++)
#pragma unroll
        for (int j = 0; j < 4; j++)
          acc[i][j] = __builtin_amdgcn_mfma_f32_16x16x32_bf16(af[i], bfv[j], acc[i][j], 0, 0, 0);
    }
    __syncthreads();
  }
  const float* ep_b = epv + (long)b * LP;
  const float* eq_b = eqv + (long)b * LQ;
  const int* mM = maskM + (long)b * LP;
  const int* mN = maskN + (long)b * LQ;
  float* UmTB = UmT + (long)b * LQ * LP;        // [q][p]
  unsigned short* ApB = Apb + (long)b * LP * LQ; // [p][q]
  unsigned short* ApTB = ApT + (long)b * LQ * LP;// [q][p]
  float eqc[4]; int mnc[4];
#pragma unroll
  for (int j = 0; j < 4; j++) {
    int col = wc + j * 16 + fr;
    eqc[j] = eq_b[col]; mnc[j] = mN[col];
  }
  float epr[2][4]; int mmr[2][4];
#pragma unroll
  for (int i = 0; i < 2; i++)
#pragma unroll
    for (int r = 0; r < 4; r++) {
      int row = m0 + wr + i * 16 + fq * 4 + r;
      epr[i][r] = ep_b[row]; mmr[i][r] = mM[row];
    }
#pragma unroll
  for (int i = 0; i < 2; i++)
#pragma unroll
    for (int j = 0; j < 4; j++) {
      float4 tv;
#pragma unroll
      for (int r = 0; r < 4; r++) {
        float a = acc[i][j][r];
        bool ok = mmr[i][r] && mnc[j];
        ((float*)&tv)[r] = ok ? a + epr[i][r] : NEG_MAX;
        acc[i][j][r] = ok ? a + eqc[j] : NEG_MAX;
      }
      int col = wc + j * 16 + fr;
      *(float4*)(UmTB + (long)col * LP + m0 + wr + i * 16 + fq * 4) = tv;
    }
  float mx[2][4];
#pragma unroll
  for (int i = 0; i < 2; i++)
#pragma unroll
    for (int r = 0; r < 4; r++) {
      float m = fmaxf(fmaxf(acc[i][0][r], acc[i][1][r]), fmaxf(acc[i][2][r], acc[i][3][r]));
#pragma unroll
      for (int s = 1; s < 16; s <<= 1) m = fmaxf(m, __shfl_xor(m, s));
      mx[i][r] = m;
      if (fr == 0) smax[wn][wr + i * 16 + fq * 4 + r] = m;
    }
  __syncthreads();
#pragma unroll
  for (int i = 0; i < 2; i++)
#pragma unroll
    for (int r = 0; r < 4; r++) {
      int rl = wr + i * 16 + fq * 4 + r;
      mx[i][r] = fmaxf(smax[0][rl], smax[1][rl]);
    }
#pragma unroll
  for (int i = 0; i < 2; i++)
#pragma unroll
    for (int r = 0; r < 4; r++) {
      float s = 0.f;
#pragma unroll
      for (int j = 0; j < 4; j++) {
        float e = __expf(acc[i][j][r] - mx[i][r]);
        acc[i][j][r] = e; s += e;
      }
#pragma unroll
      for (int sh = 1; sh < 16; sh <<= 1) s += __shfl_xor(s, sh);
      if (fr == 0) ssum[wn][wr + i * 16 + fq * 4 + r] = s;
    }
  __syncthreads();
#pragma unroll
  for (int i = 0; i < 2; i++)
#pragma unroll
    for (int r0 = 0; r0 < 4; r0++) {
      int rl = wr + i * 16 + fq * 4 + r0;
      float S = ssum[0][rl] + ssum[1][rl];
      float inv = S > 0.f ? 1.f / S : 0.f;
      int row = m0 + rl;
#pragma unroll
      for (int j = 0; j < 4; j++) {
        int col = wc + j * 16 + fr;
        bool ok = mmr[i][r0] && mnc[j];
        ApB[(long)row * LQ + col] = ok ? f2bf(acc[i][j][r0] * inv) : 0;
      }
    }
  // ApT [q][p] vector writes (4 consecutive p rows per ushort4)
#pragma unroll
  for (int i = 0; i < 2; i++)
#pragma unroll
    for (int j = 0; j < 4; j++) {
      int col = wc + j * 16 + fr;
      int row0 = m0 + wr + i * 16 + fq * 4;
      ushort4v o;
#pragma unroll
      for (int r = 0; r < 4; r++) {
        int rl = wr + i * 16 + fq * 4 + r;
        float S = ssum[0][rl] + ssum[1][rl];
        float inv = S > 0.f ? 1.f / S : 0.f;
        bool ok = mmr[i][r] && mnc[j];
        o[r] = ok ? f2bf(acc[i][j][r] * inv) : 0;
      }
      *(ushort4v*)(ApTB + (long)col * LP + row0) = o;
    }
}

// ---------------- col softmax over p (len 512) on UmT rows, wave per row -> BpT bf16 ----------------
__global__ __launch_bounds__(256) void colsoftmaxT_kernel(
    const float* __restrict__ UmT, unsigned short* __restrict__ BpT,
    const int* __restrict__ mp, const int* __restrict__ mq) {
  int wid = blockIdx.x * 4 + (threadIdx.x >> 6);  // = b*LQ + q
  int lane = threadIdx.x & 63;
  int b = wid >> 7;
  const float* row = UmT + (long)wid * LP;
  float v[8];
  float m = NEG_MAX;
#pragma unroll
  for (int i = 0; i < 8; i++) { v[i] = row[lane + 64 * i]; m = fmaxf(m, v[i]); }
#pragma unroll
  for (int off = 32; off; off >>= 1) m = fmaxf(m, __shfl_xor(m, off));
  float e[8];
  float s = 0.f;
#pragma unroll
  for (int i = 0; i < 8; i++) { e[i] = __expf(v[i] - m); s += e[i]; }
#pragma unroll
  for (int off = 32; off; off >>= 1) s += __shfl_xor(s, off);
  float inv = s > 0.f ? 1.f / s : 0.f;
  int mqv = mq[wid];
#pragma unroll
  for (int i = 0; i < 8; i++) {
    int p = lane + 64 * i;
    bool ok = mqv && mp[b * LP + p];
    BpT[(long)wid * LP + p] = ok ? f2bf(e[i] * inv) : 0;
  }
}

// ---------------- K4: main phase ----------------
// grid 640, XCD-swizzled. bx<4: B-side: B1 (K=512, co-staged M2=Bp^T@Ap) then B2=M2@Eq (K=128);
//   writes ALL 5 gpq chunks + B1T. bx>=4: A-side: A1 (K=128) -> gqp chunks 0,1,3.
__global__ __launch_bounds__(256) void phase_main(
    const unsigned short* __restrict__ Apb, const unsigned short* __restrict__ BpT,
    const unsigned short* __restrict__ ApT, const unsigned short* __restrict__ EqTg,
    const unsigned short* __restrict__ EqTa, const unsigned short* __restrict__ EpT,
    const float* __restrict__ EpF, const float* __restrict__ EqF,
    const int* __restrict__ mp, const int* __restrict__ mq,
    float* __restrict__ out_gqp, float* __restrict__ out_gpq,
    unsigned short* __restrict__ B1T) {
  const int hw = blockIdx.x;
  const int xcd = hw & 7, s_ = hw >> 3;
  const int b = xcd * 4 + (s_ / 20);
  const int bx = s_ % 20;
  __shared__ __align__(16) char smem[65536];
  unsigned short* As = (unsigned short*)smem;             // 16 KB
  unsigned short* Bs = (unsigned short*)(smem + 16384);   // 16 KB
  unsigned short* Bs2 = (unsigned short*)(smem + 32768);  // 16 KB (B-side only)
  unsigned short* M2l = (unsigned short*)(smem + 49152);  // 16 KB [128][64k] swizzled
  float (*Cs)[132] = (float(*)[132])smem;                 // aliases As/Bs post-loop
  const int t = threadIdx.x, lane = t & 63, wid = t >> 6;
  const int wr = (wid >> 1) * 64, wc = (wid & 1) * 64;
  const int fr = lane & 15, fq = lane >> 4;

  if (bx < 4) {
    // ================= B-side =================
    const int n0 = bx * 128;
    const unsigned short* A = BpT + (long)b * LQ * LP;    // [128q][512p]
    const unsigned short* Bo = EpT + (long)b * HDIM * LP; // [512h][512p]
    const unsigned short* Ao = ApT + (long)b * LQ * LP;   // [128q'][512p]
    f32x4 acc1[4][4] = {}, accm[4][4] = {};
    for (int k0 = 0; k0 < LP; k0 += 64) {
      stage128x64(A, LP, 0, k0, As, t);
      stage128x64(Bo, LP, n0, k0, Bs, t);
      stage128x64(Ao, LP, 0, k0, Bs2, t);
      __syncthreads();
#pragma unroll
      for (int ks = 0; ks < 2; ks++) {
        short8 af[4], bfv[4], mfv[4];
#pragma unroll
        for (int i = 0; i < 4; i++) {
          af[i] = fragld(As, wr + i * 16 + fr, ks, fq);
          bfv[i] = fragld(Bs, wc + i * 16 + fr, ks, fq);
          mfv[i] = fragld(Bs2, wc + i * 16 + fr, ks, fq);
        }
#pragma unroll
        for (int i = 0; i < 4; i++)
#pragma unroll
          for (int j = 0; j < 4; j++) {
            acc1[i][j] = __builtin_amdgcn_mfma_f32_16x16x32_bf16(af[i], bfv[j], acc1[i][j], 0, 0, 0);
            accm[i][j] = __builtin_amdgcn_mfma_f32_16x16x32_bf16(af[i], mfv[j], accm[i][j], 0, 0, 0);
          }
      }
      __syncthreads();
    }
    // B1T [h][q] from regs
    unsigned short* B1TB = B1T + (long)b * HDIM * LQ;
#pragma unroll
    for (int i = 0; i < 4; i++)
#pragma unroll
      for (int j = 0; j < 4; j++) {
        int col = n0 + wc + j * 16 + fr;
        int row0 = wr + i * 16 + fq * 4;
        ushort4v o = {f2bf(acc1[i][j][0]), f2bf(acc1[i][j][1]),
                      f2bf(acc1[i][j][2]), f2bf(acc1[i][j][3])};
        *(ushort4v*)(B1TB + (long)col * LQ + row0) = o;
      }
    // B2 = M2 @ EqT tile (K=128 in two 64-k halves; M2 halves dumped from accm)
    const unsigned short* BE = EqTg + (long)b * HDIM * LQ;  // [512h][128q']
    f32x4 acc2[4][4] = {};
#pragma unroll
    for (int ks2 = 0; ks2 < 2; ks2++) {
      stage128x64(BE, LQ, n0, ks2 * 64, Bs, t);
      if ((wid & 1) == ks2) {  // waves owning cols ks2*64..+63 dump their accm quadrant
#pragma unroll
        for (int i = 0; i < 4; i++)
#pragma unroll
          for (int j = 0; j < 4; j++) {
            int kk = j * 16 + fr;  // 0..63
#pragma unroll
            for (int r = 0; r < 4; r++) {
              int row = wr + i * 16 + fq * 4 + r;
              int byte = ((row << 7) + kk * 2) ^ ((row & 7) << 4);
              *(unsigned short*)((char*)M2l + byte) = f2bf(accm[i][j][r]);
            }
          }
      }
      __syncthreads();
#pragma unroll
      for (int ks = 0; ks < 2; ks++) {
        short8 af[4], bfv[4];
#pragma unroll
        for (int i = 0; i < 4; i++) {
          af[i] = fragld(M2l, wr + i * 16 + fr, ks, fq);
          bfv[i] = fragld(Bs, wc + i * 16 + fr, ks, fq);
        }
#pragma unroll
        for (int i = 0; i < 4; i++)
#pragma unroll
          for (int j = 0; j < 4; j++)
            acc2[i][j] = __builtin_amdgcn_mfma_f32_16x16x32_bf16(af[i], bfv[j], acc2[i][j], 0, 0, 0);
      }
      __syncthreads();
    }
    // epilogue: 5 gpq chunks, LDS-vectorized
    float* outB = out_gpq + (long)b * LQ * GDIM;
    const float* Eb = EqF + (long)b * LQ * HDIM;
    const int* mb = mq + (long)b * LQ;
    const int band = wid >> 1;
#pragma unroll
    for (int i = 0; i < 4; i++) {
      // pass 1: B1 slice -> chunks 0,1,3 (keep e,mm for pass 2)
      __syncthreads();
#pragma unroll
      for (int j = 0; j < 4; j++)
#pragma unroll
        for (int r = 0; r < 4; r++)
          Cs[band * 16 + fq * 4 + r][wc + j * 16 + fr] = acc1[i][j][r];
      __syncthreads();
      f32x4 ev[4]; float mmv[4]; float* orowv[4];
#pragma unroll
      for (int k = 0; k < 4; k++) {
        int slot = t + k * 256;
        int row_l = slot >> 5;
        int c4 = (slot & 31) * 4;
        int bnd = row_l >> 4;
        int r_g = bnd * 64 + i * 16 + (row_l & 15);
        mmv[k] = (float)mb[r_g];
        ev[k] = *(const f32x4*)(Eb + (long)r_g * HDIM + n0 + c4);
        orowv[k] = outB + (long)r_g * GDIM + n0 + c4;
        f32x4 v = *(f32x4*)&Cs[row_l][c4];
        f32x4 vm = v * mmv[k];
        __builtin_nontemporal_store(ev[k] * mmv[k], (f32x4*)(orowv[k]));
        __builtin_nontemporal_store(vm, (f32x4*)(orowv[k] + HDIM));
        __builtin_nontemporal_store(ev[k] * vm, (f32x4*)(orowv[k] + 3 * HDIM));
      }
      // pass 2: B2 slice -> chunks 2,4
      __syncthreads();
#pragma unroll
      for (int j = 0; j < 4; j++)
#pragma unroll
        for (int r = 0; r < 4; r++)
          Cs[band * 16 + fq * 4 + r][wc + j * 16 + fr] = acc2[i][j][r];
      __syncthreads();
#pragma unroll
      for (int k = 0; k < 4; k++) {
        int slot = t + k * 256;
        int row_l = slot >> 5;
        int c4 = (slot & 31) * 4;
        f32x4 v = *(f32x4*)&Cs[row_l][c4];
        f32x4 vm = v * mmv[k];
        __builtin_nontemporal_store(vm, (f32x4*)(orowv[k] + 2 * HDIM));
        __builtin_nontemporal_store(ev[k] * vm, (f32x4*)(orowv[k] + 4 * HDIM));
      }
    }
  } else {
    // ================= A-side: A1 = Ap @ Eq (K=128) -> gqp chunks 0,1,3 =================
    int idx = bx - 4;
    const int m0 = (idx >> 2) * 128, n0 = (idx & 3) * 128;
    const unsigned short* A = Apb + (long)b * LP * LQ;    // [512p][128q]
    const unsigned short* Bo = EqTa + (long)b * HDIM * LQ;// [512h][128q]
    f32x4 acc[4][4] = {};
    for (int k0 = 0; k0 < LQ; k0 += 64) {
      stage128x64(A, LQ, m0, k0, As, t);
      stage128x64(Bo, LQ, n0, k0, Bs, t);
      __syncthreads();
#pragma unroll
      for (int ks = 0; ks < 2; ks++) {
        short8 af[4], bfv[4];
#pragma unroll
        for (int i = 0; i < 4; i++) {
          af[i] = fragld(As, wr + i * 16 + fr, ks, fq);
          bfv[i] = fragld(Bs, wc + i * 16 + fr, ks, fq);
        }
#pragma unroll
        for (int i = 0; i < 4; i++)
#pragma unroll
          for (int j = 0; j < 4; j++)
            acc[i][j] = __builtin_amdgcn_mfma_f32_16x16x32_bf16(af[i], bfv[j], acc[i][j], 0, 0, 0);
      }
      __syncthreads();
    }
    float* outB = out_gqp + (long)b * LP * GDIM;
    const float* Eb = EpF + (long)b * LP * HDIM;
    const int* mb = mp + (long)b * LP;
    const int band = wid >> 1;
#pragma unroll
    for (int i = 0; i < 4; i++) {
      __syncthreads();
#pragma unroll
      for (int j = 0; j < 4; j++)
#pragma unroll
        for (int r = 0; r < 4; r++)
          Cs[band * 16 + fq * 4 + r][wc + j * 16 + fr] = acc[i][j][r];
      __syncthreads();
#pragma unroll
      for (int k = 0; k < 4; k++) {
        int slot = t + k * 256;
        int row_l = slot >> 5;
        int c4 = (slot & 31) * 4;
        int bnd = row_l >> 4;
        int r_g = m0 + bnd * 64 + i * 16 + (row_l & 15);
        float mm = (float)mb[r_g];
        f32x4 v = *(f32x4*)&Cs[row_l][c4];
        f32x4 e = *(const f32x4*)(Eb + (long)r_g * HDIM + n0 + c4);
        float* orow = outB + (long)r_g * GDIM + n0 + c4;
        f32x4 vm = v * mm;
        __builtin_nontemporal_store(e * mm, (f32x4*)(orow));
        __builtin_nontemporal_store(vm, (f32x4*)(orow + HDIM));
        __builtin_nontemporal_store(e * vm, (f32x4*)(orow + 3 * HDIM));
      }
    }
  }
}

// ---------------- K5: A2 = Ap @ B1 (K=128) -> gqp chunks 2,4 (512 blocks) ----------------
__global__ __launch_bounds__(256) void phase_a2(
    const unsigned short* __restrict__ Apb, const unsigned short* __restrict__ B1T,
    const float* __restrict__ EpF, const int* __restrict__ mp,
    float* __restrict__ out_gqp) {
  const int hw = blockIdx.x;
  const int xcd = hw & 7, s_ = hw >> 3;
  const int b = xcd * 4 + (s_ >> 4);
  const int idx = s_ & 15;
  const int m0 = (idx >> 2) * 128, n0 = (idx & 3) * 128;
  __shared__ __align__(16) char smem[32768];
  unsigned short* As = (unsigned short*)smem;
  unsigned short* Bs = (unsigned short*)(smem + 16384);
  float (*Cs)[132] = (float(*)[132])smem;
  const int t = threadIdx.x, lane = t & 63, wid = t >> 6;
  const int wr = (wid >> 1) * 64, wc = (wid & 1) * 64;
  const int fr = lane & 15, fq = lane >> 4;
  const unsigned short* A = Apb + (long)b * LP * LQ;    // [512p][128q]
  const unsigned short* Bo = B1T + (long)b * HDIM * LQ; // [512h][128q]
  f32x4 acc[4][4] = {};
  for (int k0 = 0; k0 < LQ; k0 += 64) {
    stage128x64(A, LQ, m0, k0, As, t);
    stage128x64(Bo, LQ, n0, k0, Bs, t);
    __syncthreads();
#pragma unroll
    for (int ks = 0; ks < 2; ks++) {
      short8 af[4], bfv[4];
#pragma unroll
      for (int i = 0; i < 4; i++) {
        af[i] = fragld(As, wr + i * 16 + fr, ks, fq);
        bfv[i] = fragld(Bs, wc + i * 16 + fr, ks, fq);
      }
#pragma unroll
      for (int i = 0; i < 4; i++)
#pragma unroll
        for (int j = 0; j < 4; j++)
          acc[i][j] = __builtin_amdgcn_mfma_f32_16x16x32_bf16(af[i], bfv[j], acc[i][j], 0, 0, 0);
    }
    __syncthreads();
  }
  float* outB = out_gqp + (long)b * LP * GDIM;
  const float* Eb = EpF + (long)b * LP * HDIM;
  const int* mb = mp + (long)b * LP;
  const int band = wid >> 1;
#pragma unroll
  for (int i = 0; i < 4; i++) {
    __syncthreads();
#pragma unroll
    for (int j = 0; j < 4; j++)
#pragma unroll
      for (int r = 0; r < 4; r++)
        Cs[band * 16 + fq * 4 + r][wc + j * 16 + fr] = acc[i][j][r];
    __syncthreads();
#pragma unroll
    for (int k = 0; k < 4; k++) {
      int slot = t + k * 256;
      int row_l = slot >> 5;
      int c4 = (slot & 31) * 4;
      int bnd = row_l >> 4;
      int r_g = m0 + bnd * 64 + i * 16 + (row_l & 15);
      float mm = (float)mb[r_g];
      f32x4 v = *(f32x4*)&Cs[row_l][c4];
      f32x4 e = *(const f32x4*)(Eb + (long)r_g * HDIM + n0 + c4);
      float* orow = outB + (long)r_g * GDIM + n0 + c4;
      f32x4 vm = v * mm;
      __builtin_nontemporal_store(vm, (f32x4*)(orow + 2 * HDIM));
      __builtin_nontemporal_store(e * vm, (f32x4*)(orow + 4 * HDIM));
    }
  }
}

extern "C" void kernel_launch(void* const* d_in, const int* in_sizes, int n_in,
                              void* d_out, int out_size, void* d_ws, size_t ws_size,
                              hipStream_t stream) {
  const float* Eq = (const float*)d_in[0];   // (32,128,512)
  const float* Ep = (const float*)d_in[1];   // (32,512,512)
  const int* mq = (const int*)d_in[2];       // (32,128)
  const int* mp = (const int*)d_in[3];       // (32,512)
  const float* w = (const float*)d_in[4];    // (1536,)
  float* out = (float*)d_out;
  float* out_gpq = out;                                  // (32,128,2560)
  float* out_gqp = out + (long)BBATCH * LQ * GDIM;       // (32,512,2560)

  unsigned short* EpT = (unsigned short*)d_ws;  // [32][512h][512p]
  unsigned short* EqT = EpT + 32L * 512 * 512;  // [32][512h][128q]
  unsigned short* Eqw = EqT + 32L * 512 * 128;  // [32][128q][512h] * wm
  unsigned short* Apb = Eqw + 32L * 128 * 512;  // [32][512p][128q]
  unsigned short* ApT = Apb + 32L * 512 * 128;  // [32][128q][512p]
  unsigned short* BpT = ApT + 32L * 128 * 512;  // [32][128q][512p]
  unsigned short* B1T = BpT + 32L * 128 * 512;  // [32][512h][128q]
  float* UmT = (float*)(B1T + 32L * 512 * 128); // [32][128q][512p]
  float* epb = UmT + 32L * 128 * 512;           // [32][512]
  float* eqb2 = epb + 32L * 512;                // [32][128]

  // 1. prep: transposes + Eqw + exact f32 bias dots
  prep_kernel<<<dim3(10, BBATCH), 256, 0, stream>>>(
      Ep, Eq, w, EpT, EqT, Eqw, epb, eqb2);

  // 2. U GEMM + fused row-softmax -> Apb, ApT, UmT
  u_gemm<<<dim3(256), 256, 0, stream>>>(
      Ep, Eqw, epb, eqb2, mp, mq, UmT, Apb, ApT);

  // 3. col softmax -> BpT
  colsoftmaxT_kernel<<<BBATCH * LQ / 4, 256, 0, stream>>>(UmT, BpT, mp, mq);

  // 4. K4: B-side {B1 + M2 + B2 -> all 5 gpq chunks + B1T}; A-side {A1 -> gqp 0,1,3}
  phase_main<<<dim3(640), 256, 0, stream>>>(
      Apb, BpT, ApT, EqT, EqT, EpT, Ep, Eq, mp, mq, out_gqp, out_gpq, B1T);

  // 5. K5: A2 = Ap@B1 -> gqp chunks 2,4
  phase_a2<<<dim3(512), 256, 0, stream>>>(
      Apb, B1T, Ep, mp, out_gqp);
}

// Round 13
// 107.125 us; speedup vs baseline: 1.0131x; 1.0131x over previous
//
#include <hip/hip_runtime.h>
#include <hip/hip_bf16.h>

// Problem constants: B=8, NUM=4 -> BB=32 batches; LQ=128, LP=512, H=512.
#define BBATCH 32
#define LQ 128
#define LP 512
#define HDIM 512
#define GDIM 2560   // 5*H concat width
#define NEG_MAX (-3.402823466e38f)

typedef __attribute__((ext_vector_type(8))) short short8;
typedef __attribute__((ext_vector_type(4))) float f32x4;
typedef __attribute__((ext_vector_type(4))) unsigned short ushort4v;

__device__ inline unsigned short f2bf(float f) {
  union { float f; unsigned int u; } v; v.f = f;
  unsigned int r = v.u + 0x7FFFu + ((v.u >> 16) & 1u);  // RNE
  return (unsigned short)(r >> 16);
}

// ---- staging / fragment helpers (rows x 64 k bf16 tiles, XOR-swizzled, 128B rows) ----
__device__ inline void stage128x64(const unsigned short* __restrict__ src, int ld,
                                   int row0, int k0, unsigned short* lds, int t) {
#pragma unroll
  for (int i = 0; i < 4; i++) {
    int o = (t + i * 256) * 16;
    int row = o >> 7, col = (o & 127) >> 1;
    int swz = o ^ ((row & 7) << 4);
    *(short8*)((char*)lds + swz) = *(const short8*)(src + (long)(row0 + row) * ld + k0 + col);
  }
}
// f32 source -> bf16 LDS (convert in-register; identical bits to pre-cast path)
__device__ inline void stage64x64_f32(const float* __restrict__ src, int ld,
                                      int row0, int k0, unsigned short* lds, int t) {
#pragma unroll
  for (int i = 0; i < 2; i++) {
    int o = (t + i * 256) * 16;
    int row = o >> 7, col = (o & 127) >> 1;
    int swz = o ^ ((row & 7) << 4);
    const float* p = src + (long)(row0 + row) * ld + k0 + col;
    float4 a = *(const float4*)p;
    float4 b2 = *(const float4*)(p + 4);
    short8 v = {(short)f2bf(a.x), (short)f2bf(a.y), (short)f2bf(a.z), (short)f2bf(a.w),
                (short)f2bf(b2.x), (short)f2bf(b2.y), (short)f2bf(b2.z), (short)f2bf(b2.w)};
    *(short8*)((char*)lds + swz) = v;
  }
}
__device__ inline short8 fragld(const unsigned short* lds, int row, int ks, int fq) {
  return *(const short8*)((const char*)lds + (((row << 7) + ks * 64 + fq * 16) ^ ((row & 7) << 4)));
}

// ---------------- prep: Ep & Eq f32 -> bf16 transposed (+ Eqw) + exact f32 bias dots ----------------
__global__ __launch_bounds__(256) void prep_kernel(
    const float* __restrict__ Ep, const float* __restrict__ Eq,
    const float* __restrict__ w,
    unsigned short* __restrict__ EpT, unsigned short* __restrict__ EqT,
    unsigned short* __restrict__ Eqw,
    float* __restrict__ epv, float* __restrict__ eqv) {
  const int b = blockIdx.y;
  const int bx = blockIdx.x;
  const bool isP = bx < 8;
  const int R = isP ? LP : LQ;
  const int p0 = (isP ? bx : bx - 8) * 64;
  const float* src = isP ? Ep + (long)b * LP * HDIM : Eq + (long)b * LQ * HDIM;
  const float* wb_base = isP ? w + HDIM : w;
  unsigned short* dT = isP ? EpT + (long)b * HDIM * LP : EqT + (long)b * HDIM * LQ;
  unsigned short* dW = isP ? nullptr : Eqw + (long)b * LQ * HDIM;
  float* bias = (isP ? epv + b * LP : eqv + b * LQ) + p0;
  __shared__ float T[64][65];
  const int t = threadIdx.x, c4 = (t & 15) * 4, r = t >> 4;
  float dot[4] = {0.f, 0.f, 0.f, 0.f};
  for (int h0 = 0; h0 < HDIM; h0 += 64) {
    float4 wb = *(const float4*)(wb_base + h0 + c4);
    float4 wm4 = {0, 0, 0, 0};
    if (!isP) wm4 = *(const float4*)(w + 2 * HDIM + h0 + c4);
    __syncthreads();
#pragma unroll
    for (int i = 0; i < 4; i++) {
      int row = r + 16 * i;
      float4 v = *(const float4*)(src + (long)(p0 + row) * HDIM + h0 + c4);
      T[row][c4] = v.x; T[row][c4 + 1] = v.y; T[row][c4 + 2] = v.z; T[row][c4 + 3] = v.w;
      if (!isP) {
        ushort4v ow = {f2bf(v.x * wm4.x), f2bf(v.y * wm4.y), f2bf(v.z * wm4.z), f2bf(v.w * wm4.w)};
        *(ushort4v*)(dW + (long)(p0 + row) * HDIM + h0 + c4) = ow;
      }
      dot[i] += v.x * wb.x + v.y * wb.y + v.z * wb.z + v.w * wb.w;
    }
    __syncthreads();
#pragma unroll
    for (int i = 0; i < 4; i++) {
      int hh = r + 16 * i;
      ushort4v o = {f2bf(T[c4][hh]), f2bf(T[c4 + 1][hh]), f2bf(T[c4 + 2][hh]), f2bf(T[c4 + 3][hh])};
      *(ushort4v*)(dT + (long)(h0 + hh) * R + p0 + c4) = o;
    }
  }
#pragma unroll
  for (int i = 0; i < 4; i++) {
#pragma unroll
    for (int s = 1; s < 16; s <<= 1) dot[i] += __shfl_xor(dot[i], s);
  }
  if ((t & 15) == 0) {
#pragma unroll
    for (int i = 0; i < 4; i++) bias[r + 16 * i] = dot[i];
  }
}

// ---------------- U GEMM (64-row M-tile) + fused row-softmax ----------------
// grid: 256 blocks 1-D, XCD-swizzled. A staged from f32 Ep; B = Eqw bf16.
__global__ __launch_bounds__(256) void u_gemm(
    const float* __restrict__ EpF, const unsigned short* __restrict__ Bb,
    const float* __restrict__ epv, const float* __restrict__ eqv,
    const int* __restrict__ maskM, const int* __restrict__ maskN,
    float* __restrict__ UmT, unsigned short* __restrict__ Apb) {
  const int hw = blockIdx.x;
  const int xcd = hw & 7, s_ = hw >> 3;
  const int b = xcd * 4 + (s_ >> 3);
  const int m0 = (s_ & 7) * 64;
  const float* A = EpF + (long)b * LP * HDIM;
  const unsigned short* B = Bb + (long)b * LQ * HDIM;
  __shared__ unsigned short As[4096];  // 64 x 64
  __shared__ unsigned short Bs[8192];  // 128 x 64
  __shared__ float smax[2][64], ssum[2][64];
  const int t = threadIdx.x, lane = t & 63, wid = t >> 6;
  const int wm = wid >> 1, wn = wid & 1;
  const int wr = wm * 32, wc = wn * 64;
  const int fr = lane & 15, fq = lane >> 4;
  f32x4 acc[2][4] = {};
  for (int k0 = 0; k0 < HDIM; k0 += 64) {
    stage64x64_f32(A, HDIM, m0, k0, As, t);
    stage128x64(B, HDIM, 0, k0, Bs, t);
    __syncthreads();
#pragma unroll
    for (int ks = 0; ks < 2; ks++) {
      short8 af[2], bfv[4];
#pragma unroll
      for (int i = 0; i < 2; i++) af[i] = fragld(As, wr + i * 16 + fr, ks, fq);
#pragma unroll
      for (int j = 0; j < 4; j++) bfv[j] = fragld(Bs, wc + j * 16 + fr, ks, fq);
#pragma unroll
      for (int i = 0; i < 2; i++)
#pragma unroll
        for (int j = 0; j < 4; j++)
          acc[i][j] = __builtin_amdgcn_mfma_f32_16x16x32_bf16(af[i], bfv[j], acc[i][j], 0, 0, 0);
    }
    __syncthreads();
  }
  const float* ep_b = epv + (long)b * LP;
  const float* eq_b = eqv + (long)b * LQ;
  const int* mM = maskM + (long)b * LP;
  const int* mN = maskN + (long)b * LQ;
  float* UmTB = UmT + (long)b * LQ * LP;        // [q][p]
  unsigned short* ApB = Apb + (long)b * LP * LQ; // [p][q]
  float eqc[4]; int mnc[4];
#pragma unroll
  for (int j = 0; j < 4; j++) {
    int col = wc + j * 16 + fr;
    eqc[j] = eq_b[col]; mnc[j] = mN[col];
  }
  float epr[2][4]; int mmr[2][4];
#pragma unroll
  for (int i = 0; i < 2; i++)
#pragma unroll
    for (int r = 0; r < 4; r++) {
      int row = m0 + wr + i * 16 + fq * 4 + r;
      epr[i][r] = ep_b[row]; mmr[i][r] = mM[row];
    }
#pragma unroll
  for (int i = 0; i < 2; i++)
#pragma unroll
    for (int j = 0; j < 4; j++) {
      float4 tv;
#pragma unroll
      for (int r = 0; r < 4; r++) {
        float a = acc[i][j][r];
        bool ok = mmr[i][r] && mnc[j];
        ((float*)&tv)[r] = ok ? a + epr[i][r] : NEG_MAX;
        acc[i][j][r] = ok ? a + eqc[j] : NEG_MAX;
      }
      int col = wc + j * 16 + fr;
      *(float4*)(UmTB + (long)col * LP + m0 + wr + i * 16 + fq * 4) = tv;
    }
  float mx[2][4];
#pragma unroll
  for (int i = 0; i < 2; i++)
#pragma unroll
    for (int r = 0; r < 4; r++) {
      float m = fmaxf(fmaxf(acc[i][0][r], acc[i][1][r]), fmaxf(acc[i][2][r], acc[i][3][r]));
#pragma unroll
      for (int s = 1; s < 16; s <<= 1) m = fmaxf(m, __shfl_xor(m, s));
      mx[i][r] = m;
      if (fr == 0) smax[wn][wr + i * 16 + fq * 4 + r] = m;
    }
  __syncthreads();
#pragma unroll
  for (int i = 0; i < 2; i++)
#pragma unroll
    for (int r = 0; r < 4; r++) {
      int rl = wr + i * 16 + fq * 4 + r;
      mx[i][r] = fmaxf(smax[0][rl], smax[1][rl]);
    }
#pragma unroll
  for (int i = 0; i < 2; i++)
#pragma unroll
    for (int r = 0; r < 4; r++) {
      float s = 0.f;
#pragma unroll
      for (int j = 0; j < 4; j++) {
        float e = __expf(acc[i][j][r] - mx[i][r]);
        acc[i][j][r] = e; s += e;
      }
#pragma unroll
      for (int sh = 1; sh < 16; sh <<= 1) s += __shfl_xor(s, sh);
      if (fr == 0) ssum[wn][wr + i * 16 + fq * 4 + r] = s;
    }
  __syncthreads();
#pragma unroll
  for (int i = 0; i < 2; i++)
#pragma unroll
    for (int r = 0; r < 4; r++) {
      int rl = wr + i * 16 + fq * 4 + r;
      float S = ssum[0][rl] + ssum[1][rl];
      float inv = S > 0.f ? 1.f / S : 0.f;
      int row = m0 + rl;
#pragma unroll
      for (int j = 0; j < 4; j++) {
        int col = wc + j * 16 + fr;
        bool ok = mmr[i][r] && mnc[j];
        ApB[(long)row * LQ + col] = ok ? f2bf(acc[i][j][r] * inv) : 0;
      }
    }
}

// ---------------- col softmax over p (len 512) on UmT rows, wave per row -> BpT bf16 ----------------
__global__ __launch_bounds__(256) void colsoftmaxT_kernel(
    const float* __restrict__ UmT, unsigned short* __restrict__ BpT,
    const int* __restrict__ mp, const int* __restrict__ mq) {
  int wid = blockIdx.x * 4 + (threadIdx.x >> 6);  // = b*LQ + q
  int lane = threadIdx.x & 63;
  int b = wid >> 7;
  const float* row = UmT + (long)wid * LP;
  float v[8];
  float m = NEG_MAX;
#pragma unroll
  for (int i = 0; i < 8; i++) { v[i] = row[lane + 64 * i]; m = fmaxf(m, v[i]); }
#pragma unroll
  for (int off = 32; off; off >>= 1) m = fmaxf(m, __shfl_xor(m, off));
  float e[8];
  float s = 0.f;
#pragma unroll
  for (int i = 0; i < 8; i++) { e[i] = __expf(v[i] - m); s += e[i]; }
#pragma unroll
  for (int off = 32; off; off >>= 1) s += __shfl_xor(s, off);
  float inv = s > 0.f ? 1.f / s : 0.f;
  int mqv = mq[wid];
#pragma unroll
  for (int i = 0; i < 8; i++) {
    int p = lane + 64 * i;
    bool ok = mqv && mp[b * LP + p];
    BpT[(long)wid * LP + p] = ok ? f2bf(e[i] * inv) : 0;
  }
}

// ---------------- phase GEMMs ----------------
// grid: 640 blocks 1-D, XCD-swizzled. tile<4: B-side (M=128q, K=512); else A-side (M=512p, K=128).
// Epilogue: acc slices staged via LDS -> float4 nt stores; E read as f32 float4.
template <int PHASE>
__global__ __launch_bounds__(256) void gemm_phase(
    const unsigned short* __restrict__ Apb, const unsigned short* __restrict__ BpT,
    const unsigned short* __restrict__ BA, const unsigned short* __restrict__ BB,
    const float* __restrict__ EpF, const float* __restrict__ EqF,
    const int* __restrict__ mp, const int* __restrict__ mq,
    float* __restrict__ out_gqp, float* __restrict__ out_gpq,
    unsigned short* __restrict__ A1T, unsigned short* __restrict__ B1T) {
  const int hw = blockIdx.x;
  const int xcd = hw & 7, s_ = hw >> 3;
  const int b = xcd * 4 + (s_ / 20);
  const int bx = s_ % 20;
  __shared__ __align__(16) char smem[32768];
  unsigned short* As = (unsigned short*)smem;
  unsigned short* Bs = (unsigned short*)(smem + 16384);
  float (*Cs)[132] = (float(*)[132])smem;  // aliases As/Bs after K-loop
  const int t = threadIdx.x, lane = t & 63, wid = t >> 6;
  const int wr = (wid >> 1) * 64, wc = (wid & 1) * 64;
  const int fr = lane & 15, fq = lane >> 4;
  const unsigned short* A; const unsigned short* Bop;
  int K, M, m0, n0;
  float* outBase; const float* Eb; const int* mb;
  unsigned short* Tout;
  if (bx < 4) {  // B-side
    A = BpT + (long)b * LQ * LP; K = LP; M = LQ; m0 = 0; n0 = bx * 128;
    Bop = BB + (long)b * HDIM * LP;
    outBase = out_gpq + (long)b * LQ * GDIM;
    Eb = EqF + (long)b * LQ * HDIM; mb = mq + (long)b * LQ;
    Tout = (PHASE == 1) ? B1T + (long)b * HDIM * LQ : nullptr;
  } else {       // A-side
    int idx = bx - 4; m0 = (idx >> 2) * 128; n0 = (idx & 3) * 128;
    A = Apb + (long)b * LP * LQ; K = LQ; M = LP;
    Bop = BA + (long)b * HDIM * LQ;
    outBase = out_gqp + (long)b * LP * GDIM;
    Eb = EpF + (long)b * LP * HDIM; mb = mp + (long)b * LP;
    Tout = (PHASE == 1) ? A1T + (long)b * HDIM * LP : nullptr;
  }
  f32x4 acc[4][4] = {};
  for (int k0 = 0; k0 < K; k0 += 64) {
    stage128x64(A, K, m0, k0, As, t);
    stage128x64(Bop, K, n0, k0, Bs, t);
    __syncthreads();
#pragma unroll
    for (int ks = 0; ks < 2; ks++) {
      short8 af[4], bfv[4];
#pragma unroll
      for (int i = 0; i < 4; i++) {
        af[i] = fragld(As, wr + i * 16 + fr, ks, fq);
        bfv[i] = fragld(Bs, wc + i * 16 + fr, ks, fq);
      }
#pragma unroll
      for (int i = 0; i < 4; i++)
#pragma unroll
        for (int j = 0; j < 4; j++)
          acc[i][j] = __builtin_amdgcn_mfma_f32_16x16x32_bf16(af[i], bfv[j], acc[i][j], 0, 0, 0);
    }
    __syncthreads();
  }
  // ---- Tout (A1T/B1T) bf16 transposed writes (from regs) ----
  if (PHASE == 1) {
#pragma unroll
    for (int i = 0; i < 4; i++)
#pragma unroll
      for (int j = 0; j < 4; j++) {
        int col = n0 + wc + j * 16 + fr;
        int row0 = m0 + wr + i * 16 + fq * 4;
        ushort4v o = {f2bf(acc[i][j][0]), f2bf(acc[i][j][1]),
                      f2bf(acc[i][j][2]), f2bf(acc[i][j][3])};
        *(ushort4v*)(Tout + (long)col * M + row0) = o;
      }
  }
  // ---- 5-chunk output: LDS-vectorized, float4 nt stores + f32 E float4 loads ----
  const int band = wid >> 1;
#pragma unroll
  for (int i = 0; i < 4; i++) {
    __syncthreads();  // previous slice reads done (and K-loop LDS reads for i=0)
#pragma unroll
    for (int j = 0; j < 4; j++) {
#pragma unroll
      for (int r = 0; r < 4; r++)
        Cs[band * 16 + fq * 4 + r][wc + j * 16 + fr] = acc[i][j][r];
    }
    __syncthreads();
#pragma unroll
    for (int k = 0; k < 4; k++) {
      int slot = t + k * 256;          // 0..1023
      int row_l = slot >> 5;           // 0..31
      int c4 = (slot & 31) * 4;        // 0..124
      int bnd = row_l >> 4;
      int r_g = m0 + bnd * 64 + i * 16 + (row_l & 15);
      float mm = (float)mb[r_g];
      f32x4 v = *(f32x4*)&Cs[row_l][c4];
      f32x4 e = *(const f32x4*)(Eb + (long)r_g * HDIM + n0 + c4);
      float* orow = outBase + (long)r_g * GDIM + n0 + c4;
      f32x4 vm = v * mm;
      f32x4 evm = e * vm;
      if (PHASE == 1) {
        __builtin_nontemporal_store(e * mm, (f32x4*)(orow));
        __builtin_nontemporal_store(vm, (f32x4*)(orow + HDIM));
        __builtin_nontemporal_store(evm, (f32x4*)(orow + 3 * HDIM));
      } else {
        __builtin_nontemporal_store(vm, (f32x4*)(orow + 2 * HDIM));
        __builtin_nontemporal_store(evm, (f32x4*)(orow + 4 * HDIM));
      }
    }
  }
}

extern "C" void kernel_launch(void* const* d_in, const int* in_sizes, int n_in,
                              void* d_out, int out_size, void* d_ws, size_t ws_size,
                              hipStream_t stream) {
  const float* Eq = (const float*)d_in[0];   // (32,128,512)
  const float* Ep = (const float*)d_in[1];   // (32,512,512)
  const int* mq = (const int*)d_in[2];       // (32,128)
  const int* mp = (const int*)d_in[3];       // (32,512)
  const float* w = (const float*)d_in[4];    // (1536,)
  float* out = (float*)d_out;
  float* out_gpq = out;                                  // (32,128,2560)
  float* out_gqp = out + (long)BBATCH * LQ * GDIM;       // (32,512,2560)

  unsigned short* EpT = (unsigned short*)d_ws;  // [32][512h][512p]
  unsigned short* EqT = EpT + 32L * 512 * 512;  // [32][512h][128q]
  unsigned short* Eqw = EqT + 32L * 512 * 128;  // [32][128q][512h] * wm
  unsigned short* Apb = Eqw + 32L * 128 * 512;  // [32][512p][128q]
  unsigned short* BpT = Apb + 32L * 512 * 128;  // [32][128q][512p]
  unsigned short* B1T = BpT + 32L * 128 * 512;  // [32][512h][128q]
  unsigned short* A1T = B1T + 32L * 512 * 128;  // [32][512h][512p]
  float* UmT = (float*)(A1T + 32L * 512 * 512); // [32][128q][512p]
  float* epb = UmT + 32L * 128 * 512;           // [32][512]
  float* eqb2 = epb + 32L * 512;                // [32][128]

  // 1. prep: transposes + Eqw + exact f32 bias dots
  prep_kernel<<<dim3(10, BBATCH), 256, 0, stream>>>(
      Ep, Eq, w, EpT, EqT, Eqw, epb, eqb2);

  // 2. U GEMM (A from f32 Ep) + fused row-softmax -> Apb, UmT
  u_gemm<<<dim3(256), 256, 0, stream>>>(
      Ep, Eqw, epb, eqb2, mp, mq, UmT, Apb);

  // 3. col softmax -> BpT
  colsoftmaxT_kernel<<<BBATCH * LQ / 4, 256, 0, stream>>>(UmT, BpT, mp, mq);

  // 4. phase 1: B1 (gpq 0,1,3 + B1T) and A1 (gqp 0,1,3 + A1T)   [640 blocks]
  gemm_phase<1><<<dim3(640), 256, 0, stream>>>(
      Apb, BpT, EqT, EpT, Ep, Eq, mp, mq, out_gqp, out_gpq, A1T, B1T);

  // 5. phase 2: B2 = Bp^T@A1 (gpq 2,4) and A2 = Ap@B1 (gqp 2,4) [640 blocks]
  gemm_phase<2><<<dim3(640), 256, 0, stream>>>(
      Apb, BpT, B1T, A1T, Ep, Eq, mp, mq, out_gqp, out_gpq, nullptr, nullptr);
}